// Round 1
// baseline (109.969 us; speedup 1.0000x reference)
//
#include <hip/hip_runtime.h>
#include <math.h>

namespace {
constexpr int D = 128;
constexpr int K = 8;
constexpr float BOUND = 3.0f;
constexpr float EPS = 1e-6f;
constexpr float MIN_BIN_W = 1e-3f;
constexpr float MIN_BIN_H = 1e-3f;
constexpr float MIN_DERIV = 1e-3f;
constexpr int STRIDE = 63;   // 8 bins x 7 fields + 7 search knots; odd => LDS conflict-free
constexpr int WPB = 4;       // waves per 256-thread block
}

__global__ __launch_bounds__(256) void spline_fwd(
    const float* __restrict__ x,
    const float* __restrict__ uw,
    const float* __restrict__ uh,
    const float* __restrict__ ud,
    float* __restrict__ out_u,
    float* __restrict__ out_ld,
    int nrows)
{
    __shared__ float s_tab[D * STRIDE];

    const int tid = threadIdx.x;
    if (tid < D) {
        const int d = tid;
        float wv[K], hv[K], cw[K + 1], ch[K + 1], der[K + 1];

        // softmax over unnormalized widths
        {
            const float* p = uw + d * K;
            float m = p[0];
            #pragma unroll
            for (int j = 1; j < K; ++j) m = fmaxf(m, p[j]);
            float s = 0.f;
            #pragma unroll
            for (int j = 0; j < K; ++j) { wv[j] = __expf(p[j] - m); s += wv[j]; }
            const float inv = 1.f / s;
            #pragma unroll
            for (int j = 0; j < K; ++j)
                wv[j] = MIN_BIN_W + (1.f - MIN_BIN_W * K) * (wv[j] * inv);
        }
        // softmax over unnormalized heights
        {
            const float* p = uh + d * K;
            float m = p[0];
            #pragma unroll
            for (int j = 1; j < K; ++j) m = fmaxf(m, p[j]);
            float s = 0.f;
            #pragma unroll
            for (int j = 0; j < K; ++j) { hv[j] = __expf(p[j] - m); s += hv[j]; }
            const float inv = 1.f / s;
            #pragma unroll
            for (int j = 0; j < K; ++j)
                hv[j] = MIN_BIN_H + (1.f - MIN_BIN_H * K) * (hv[j] * inv);
        }
        // knot positions (cumsum, scale to [-BOUND, BOUND], pin endpoints)
        cw[0] = -BOUND; ch[0] = -BOUND;
        float cs_w = 0.f, cs_h = 0.f;
        #pragma unroll
        for (int j = 0; j < K; ++j) {
            cs_w += wv[j]; cw[j + 1] = 2.f * BOUND * cs_w - BOUND;
            cs_h += hv[j]; ch[j + 1] = 2.f * BOUND * cs_h - BOUND;
        }
        cw[K] = BOUND; ch[K] = BOUND;

        // derivatives: softplus + MIN_DERIV, boundary = 1 - MIN_DERIV
        der[0] = 1.f - MIN_DERIV;
        der[K] = 1.f - MIN_DERIV;
        {
            const float* p = ud + d * (K - 1);
            #pragma unroll
            for (int j = 1; j < K; ++j) {
                const float v = p[j - 1];
                const float sp = log1pf(__expf(-fabsf(v))) + fmaxf(v, 0.f);
                der[j] = MIN_DERIV + sp;
            }
        }

        float* row = s_tab + d * STRIDE;
        #pragma unroll
        for (int j = 0; j < K; ++j) {
            const float w = cw[j + 1] - cw[j];
            const float h = ch[j + 1] - ch[j];
            row[j * 7 + 0] = 1.f / w;     // inverse bin width
            row[j * 7 + 1] = cw[j];
            row[j * 7 + 2] = ch[j];
            row[j * 7 + 3] = h / w;       // delta
            row[j * 7 + 4] = der[j];
            row[j * 7 + 5] = der[j + 1];
            row[j * 7 + 6] = h;
        }
        #pragma unroll
        for (int j = 0; j < K - 1; ++j) row[56 + j] = cw[j + 1];  // interior knots for search
    }
    __syncthreads();

    const int wave = tid >> 6;
    const int lane = tid & 63;
    const int rstep = gridDim.x * WPB;

    for (int r = blockIdx.x * WPB + wave; r < nrows; r += rstep) {
        const float* xr = x + (size_t)r * D;
        float* ur = out_u + (size_t)r * D;
        float lacc = 0.f;
        #pragma unroll
        for (int half = 0; half < 2; ++half) {
            const int d = lane + half * 64;
            const float xv = xr[d];
            const bool inside = (xv >= -BOUND) & (xv <= BOUND);
            const float xc = fminf(fmaxf(xv, -BOUND), BOUND);
            const float* row = s_tab + d * STRIDE;

            int idx = 0;
            #pragma unroll
            for (int j = 0; j < K - 1; ++j)
                idx += (xc >= row[56 + j] + EPS) ? 1 : 0;

            const float* t = row + idx * 7;
            const float inv_w = t[0];
            const float icw   = t[1];
            const float ich   = t[2];
            const float dl    = t[3];
            const float d0    = t[4];
            const float d1    = t[5];
            const float ih    = t[6];

            const float theta = (xc - icw) * inv_w;
            const float omt   = 1.f - theta;
            const float t1m   = theta * omt;
            const float th2   = theta * theta;
            const float num   = ih * (dl * th2 + d0 * t1m);
            const float den   = dl + (d0 + d1 - 2.f * dl) * t1m;
            const float outv  = ich + __fdividef(num, den);
            const float dnum  = dl * dl * (d1 * th2 + 2.f * dl * t1m + d0 * omt * omt);
            const float lad   = __logf(dnum) - 2.f * __logf(den);

            ur[d] = inside ? outv : xv;
            lacc += inside ? lad : 0.f;
        }
        #pragma unroll
        for (int off = 32; off > 0; off >>= 1)
            lacc += __shfl_down(lacc, off);
        if (lane == 0) out_ld[r] = lacc;
    }
}

extern "C" void kernel_launch(void* const* d_in, const int* in_sizes, int n_in,
                              void* d_out, int out_size, void* d_ws, size_t ws_size,
                              hipStream_t stream) {
    const float* x  = (const float*)d_in[0];
    const float* uw = (const float*)d_in[1];
    const float* uh = (const float*)d_in[2];
    const float* ud = (const float*)d_in[3];
    const int nrows = in_sizes[0] / D;
    float* out_u  = (float*)d_out;
    float* out_ld = (float*)d_out + (size_t)nrows * D;
    spline_fwd<<<1280, 256, 0, stream>>>(x, uw, uh, ud, out_u, out_ld, nrows);
}

// Round 2
// 103.197 us; speedup vs baseline: 1.0656x; 1.0656x over previous
//
#include <hip/hip_runtime.h>
#include <math.h>

namespace {
constexpr int D = 128;
constexpr int K = 8;
constexpr float BOUND = 3.0f;
constexpr float EPS = 1e-6f;
constexpr float MIN_BIN_W = 1e-3f;
constexpr float MIN_BIN_H = 1e-3f;
constexpr float MIN_DERIV = 1e-3f;
constexpr int REC = 8;           // floats per (dim,bin) record, 16B-aligned pairs of float4
constexpr int S = K * REC + 4;   // 68 floats per dim row: keeps 16B align, staggers banks by 4d
constexpr int WPB = 4;           // waves per 256-thread block
}

// record layout: ra = {icw, inv_w, d0, delta}, rb = {ich, ih, d1, E=d0+d1-2*delta}
__device__ __forceinline__ float spline_one(float xv, const float* __restrict__ row,
                                            const float* kn, float* __restrict__ outp) {
    const bool inside = (xv >= -BOUND) & (xv <= BOUND);
    const float xc = fminf(fmaxf(xv, -BOUND), BOUND);
    int idx = 0;
    #pragma unroll
    for (int j = 0; j < 7; ++j) idx += (xc >= kn[j]) ? 1 : 0;
    const float4 ra = *(const float4*)(row + idx * REC);
    const float4 rb = *(const float4*)(row + idx * REC + 4);
    const float theta = (xc - ra.x) * ra.y;
    const float omt   = 1.f - theta;
    const float t1m   = theta * omt;
    const float th2   = theta * theta;
    const float num   = rb.y * (ra.w * th2 + ra.z * t1m);
    const float den   = ra.w + rb.w * t1m;
    const float outv  = rb.x + __fdividef(num, den);
    const float dnum  = ra.w * ra.w * (rb.z * th2 + 2.f * ra.w * t1m + ra.z * omt * omt);
    const float lad   = __logf(dnum) - 2.f * __logf(den);
    *outp = inside ? outv : xv;
    return inside ? lad : 0.f;
}

__global__ __launch_bounds__(256) void spline_fwd(
    const float* __restrict__ x,
    const float* __restrict__ uw,
    const float* __restrict__ uh,
    const float* __restrict__ ud,
    float* __restrict__ out_u,
    float* __restrict__ out_ld,
    int nrows)
{
    __shared__ __align__(16) float s_tab[D * S];

    const int tid = threadIdx.x;
    if (tid < D) {
        const int d = tid;
        float wv[K], hv[K], cw[K + 1], ch[K + 1], der[K + 1];

        // softmax over unnormalized widths
        {
            const float* p = uw + d * K;
            float m = p[0];
            #pragma unroll
            for (int j = 1; j < K; ++j) m = fmaxf(m, p[j]);
            float s = 0.f;
            #pragma unroll
            for (int j = 0; j < K; ++j) { wv[j] = __expf(p[j] - m); s += wv[j]; }
            const float inv = 1.f / s;
            #pragma unroll
            for (int j = 0; j < K; ++j)
                wv[j] = MIN_BIN_W + (1.f - MIN_BIN_W * K) * (wv[j] * inv);
        }
        // softmax over unnormalized heights
        {
            const float* p = uh + d * K;
            float m = p[0];
            #pragma unroll
            for (int j = 1; j < K; ++j) m = fmaxf(m, p[j]);
            float s = 0.f;
            #pragma unroll
            for (int j = 0; j < K; ++j) { hv[j] = __expf(p[j] - m); s += hv[j]; }
            const float inv = 1.f / s;
            #pragma unroll
            for (int j = 0; j < K; ++j)
                hv[j] = MIN_BIN_H + (1.f - MIN_BIN_H * K) * (hv[j] * inv);
        }
        // knots (cumsum, scale to [-BOUND,BOUND], pin endpoints)
        cw[0] = -BOUND; ch[0] = -BOUND;
        float cs_w = 0.f, cs_h = 0.f;
        #pragma unroll
        for (int j = 0; j < K; ++j) {
            cs_w += wv[j]; cw[j + 1] = 2.f * BOUND * cs_w - BOUND;
            cs_h += hv[j]; ch[j + 1] = 2.f * BOUND * cs_h - BOUND;
        }
        cw[K] = BOUND; ch[K] = BOUND;

        // derivatives: softplus + MIN_DERIV, boundaries = 1 - MIN_DERIV
        der[0] = 1.f - MIN_DERIV;
        der[K] = 1.f - MIN_DERIV;
        {
            const float* p = ud + d * (K - 1);
            #pragma unroll
            for (int j = 1; j < K; ++j) {
                const float v = p[j - 1];
                const float sp = log1pf(__expf(-fabsf(v))) + fmaxf(v, 0.f);
                der[j] = MIN_DERIV + sp;
            }
        }

        float* row = s_tab + d * S;
        #pragma unroll
        for (int j = 0; j < K; ++j) {
            const float w  = cw[j + 1] - cw[j];
            const float h  = ch[j + 1] - ch[j];
            const float dl = h / w;
            row[j * REC + 0] = cw[j];
            row[j * REC + 1] = 1.f / w;
            row[j * REC + 2] = der[j];
            row[j * REC + 3] = dl;
            row[j * REC + 4] = ch[j];
            row[j * REC + 5] = h;
            row[j * REC + 6] = der[j + 1];
            row[j * REC + 7] = der[j] + der[j + 1] - 2.f * dl;
        }
    }
    __syncthreads();

    const int wave = tid >> 6;
    const int lane = tid & 63;
    const int da = lane;          // this lane's two fixed dims
    const int db = lane + 64;
    const float* rowa = s_tab + da * S;
    const float* rowb = s_tab + db * S;

    // hoist interior knots (+EPS folded in) into registers: icw of bin j IS knot j
    float kna[7], knb[7];
    #pragma unroll
    for (int j = 0; j < 7; ++j) {
        kna[j] = rowa[(j + 1) * REC] + EPS;
        knb[j] = rowb[(j + 1) * REC] + EPS;
    }

    const int rstep = gridDim.x * WPB;
    for (int r = blockIdx.x * WPB + wave; r < nrows; r += rstep) {
        const float* xr = x + (size_t)r * D;
        float* ur = out_u + (size_t)r * D;
        const float xa = xr[da];
        const float xb = xr[db];
        float lacc = spline_one(xa, rowa, kna, ur + da)
                   + spline_one(xb, rowb, knb, ur + db);
        #pragma unroll
        for (int off = 32; off > 0; off >>= 1)
            lacc += __shfl_down(lacc, off);
        if (lane == 0) out_ld[r] = lacc;
    }
}

extern "C" void kernel_launch(void* const* d_in, const int* in_sizes, int n_in,
                              void* d_out, int out_size, void* d_ws, size_t ws_size,
                              hipStream_t stream) {
    const float* x  = (const float*)d_in[0];
    const float* uw = (const float*)d_in[1];
    const float* uh = (const float*)d_in[2];
    const float* ud = (const float*)d_in[3];
    const int nrows = in_sizes[0] / D;
    float* out_u  = (float*)d_out;
    float* out_ld = (float*)d_out + (size_t)nrows * D;
    // grid 1024 = exactly 4 blocks/CU at 34.8 KB LDS -> 16 waves/CU, no tail imbalance
    spline_fwd<<<1024, 256, 0, stream>>>(x, uw, uh, ud, out_u, out_ld, nrows);
}